// Round 11
// baseline (203.743 us; speedup 1.0000x reference)
//
#include <hip/hip_runtime.h>
#include <hip/hip_bf16.h>

// GraphPosteriorHead: B=32, N=64, D=256
// Pipeline:
//  K0: ctx projections (6x (32,256))       -> ws
//  K1: split encoder chains; COL-SPLIT (wave owns 32 cols, full K=256,
//      no cross-wave reduction, 25KB LDS, 4 barriers/block)
//  K3: edge logits + entropy; split by predictor, dbuf fjt staging
//  K6: gate + combine + W_posterior + expm; 512 thr, PS Taylor-13, thr 2.0
//  K7: acyc reduction -> out[131072]

#define LDS_STRIDE 260   // 256 + 4 pad
#define ES 68            // expm LDS row stride

// Branch-free gelu: erf via Abramowitz-Stegun 7.1.26 (|abs err| <= 1.5e-7).
// Uses v_rcp_f32: a precise 1.0f/x lowers to the ~11-op div sequence (r6 lesson).
__device__ __forceinline__ float gelu_f(float x) {
    float z = fabsf(x) * 0.70710678118654752440f;
    float t = __builtin_amdgcn_rcpf(fmaf(0.3275911f, z, 1.0f));
    float p = t * fmaf(t, fmaf(t, fmaf(t, fmaf(t, 1.061405429f, -1.453152027f),
                                       1.421413741f), -0.284496736f), 0.254829592f);
    float e = __expf(-z * z);
    float erfv = fmaf(-p, e, 1.0f);
    erfv = copysignf(erfv, x);
    return 0.5f * x * (1.0f + erfv);
}
__device__ __forceinline__ float sigmoid_f(float x) {
    return 1.0f / (1.0f + expf(-x));
}
__device__ __forceinline__ float f4c(const float4& v, int k) {
    return k == 0 ? v.x : k == 1 ? v.y : k == 2 ? v.z : v.w;
}
__device__ __forceinline__ float4 ld4(const float* __restrict__ buf, int r, int c) {
    return *(const float4*)&buf[r * ES + c];
}

// ---------------- K0: context projections ----------------
__global__ __launch_bounds__(256) void k0_ctx(
    const float* __restrict__ ds, const float* __restrict__ cc,
    const float* __restrict__ dge_w1, const float* __restrict__ dge_b1,
    const float* __restrict__ cge_w1, const float* __restrict__ cge_b1,
    const float* __restrict__ dep_w1, const float* __restrict__ dep_b1,
    const float* __restrict__ cep_w1, const float* __restrict__ cep_b1,
    float* __restrict__ ctxproj)
{
    const int b = blockIdx.x;
    const int which = blockIdx.y;
    const float* ctx; const float* W; const float* bias;
    switch (which) {
        case 0:  ctx = ds; W = dge_w1 + 256 * 256; bias = dge_b1; break;
        case 1:  ctx = cc; W = cge_w1 + 256 * 256; bias = cge_b1; break;
        case 2:  ctx = ds; W = dep_w1 + 256 * 256; bias = dep_b1; break;
        case 3:  ctx = ds; W = dep_w1 + 768 * 256; bias = nullptr; break;
        case 4:  ctx = cc; W = cep_w1 + 256 * 256; bias = cep_b1; break;
        default: ctx = cc; W = cep_w1 + 768 * 256; bias = nullptr; break;
    }
    __shared__ float sctx[256];
    const int tid = threadIdx.x;
    sctx[tid] = ctx[b * 256 + tid];
    __syncthreads();
    float acc = 0.0f;
    #pragma unroll 2
    for (int k = 0; k < 256; k += 4) {
        float4 c4 = *(const float4*)&sctx[k];
        acc = fmaf(c4.x, W[(k + 0) * 256 + tid], acc);
        acc = fmaf(c4.y, W[(k + 1) * 256 + tid], acc);
        acc = fmaf(c4.z, W[(k + 2) * 256 + tid], acc);
        acc = fmaf(c4.w, W[(k + 3) * 256 + tid], acc);
    }
    if (bias) acc += bias[tid];
    ctxproj[(which * 32 + b) * 256 + tid] = acc;
}

// ---------------- K1: split encoder chains, COL-SPLIT ----------------
// Each lane: one row r, 4 cols c0..c0+3, full K=256 sequential accumulation.
__device__ __forceinline__ void gemm_cs(const float* __restrict__ src,  // LDS [8][LDS_STRIDE]
                                        const float* __restrict__ W,    // global [256][256]
                                        int r, int c0, float acc[4])
{
    acc[0] = acc[1] = acc[2] = acc[3] = 0.0f;
    #pragma unroll 2
    for (int k = 0; k < 256; k += 4) {
        float4 a  = *(const float4*)&src[r * LDS_STRIDE + k];
        float4 w0 = *(const float4*)&W[(k + 0) * 256 + c0];
        float4 w1 = *(const float4*)&W[(k + 1) * 256 + c0];
        float4 w2 = *(const float4*)&W[(k + 2) * 256 + c0];
        float4 w3 = *(const float4*)&W[(k + 3) * 256 + c0];
        acc[0] = fmaf(a.x, w0.x, acc[0]);
        acc[1] = fmaf(a.x, w0.y, acc[1]);
        acc[2] = fmaf(a.x, w0.z, acc[2]);
        acc[3] = fmaf(a.x, w0.w, acc[3]);
        acc[0] = fmaf(a.y, w1.x, acc[0]);
        acc[1] = fmaf(a.y, w1.y, acc[1]);
        acc[2] = fmaf(a.y, w1.z, acc[2]);
        acc[3] = fmaf(a.y, w1.w, acc[3]);
        acc[0] = fmaf(a.z, w2.x, acc[0]);
        acc[1] = fmaf(a.z, w2.y, acc[1]);
        acc[2] = fmaf(a.z, w2.z, acc[2]);
        acc[3] = fmaf(a.z, w2.w, acc[3]);
        acc[0] = fmaf(a.w, w3.x, acc[0]);
        acc[1] = fmaf(a.w, w3.y, acc[1]);
        acc[2] = fmaf(a.w, w3.z, acc[2]);
        acc[3] = fmaf(a.w, w3.w, acc[3]);
    }
}

// grid 512: blk = (((b*8)+chunk)*2)+chain. chain 0 = dge->dep, 1 = cge->cep.
__global__ __launch_bounds__(512, 4) void k1_encode(
    const float* __restrict__ ve_g,
    const float* __restrict__ dge_w1, const float* __restrict__ dge_w2, const float* __restrict__ dge_b2,
    const float* __restrict__ cge_w1, const float* __restrict__ cge_w2, const float* __restrict__ cge_b2,
    const float* __restrict__ dep_w1, const float* __restrict__ cep_w1,
    const float* __restrict__ ctxproj,
    float* __restrict__ fi_dep, float* __restrict__ fjt_dep,
    float* __restrict__ fi_cep, float* __restrict__ fjt_cep)
{
    __shared__ float sve[8 * LDS_STRIDE];
    __shared__ float sA[8 * LDS_STRIDE];
    __shared__ float sB[8 * LDS_STRIDE];   // 25 KB total

    const int tid   = threadIdx.x;
    const int blk   = blockIdx.x;
    const int chain = blk & 1;
    const int chunk = (blk >> 1) & 7;
    const int b     = blk >> 4;
    const int n0    = chunk * 8;

    const float* w1   = chain ? cge_w1 : dge_w1;
    const float* w2   = chain ? cge_w2 : dge_w2;
    const float* b2   = chain ? cge_b2 : dge_b2;
    const float* epw  = chain ? cep_w1 : dep_w1;
    float* fi  = chain ? fi_cep  : fi_dep;
    float* fjt = chain ? fjt_cep : fjt_dep;
    const int cp_s1 = chain ? 1 : 0;
    const int cp_fi = chain ? 4 : 2;
    const int cp_fj = chain ? 5 : 3;

    const int w  = tid >> 6;              // wave 0..7: cols [32w, 32w+32)
    const int l  = tid & 63;
    const int r  = l >> 3;                // row 0..7
    const int c0 = w * 32 + (l & 7) * 4;  // 4-col slice

    // register-prefetch per-column epilogue vectors
    float4 cp1 = *(const float4*)&ctxproj[(cp_s1 * 32 + b) * 256 + c0];
    float4 bv2 = *(const float4*)&b2[c0];
    float4 cpf = *(const float4*)&ctxproj[(cp_fi * 32 + b) * 256 + c0];
    float4 cpj = *(const float4*)&ctxproj[(cp_fj * 32 + b) * 256 + c0];

    {
        int idx = tid * 4;
        int rr = idx >> 8, k = idx & 255;
        *(float4*)&sve[rr * LDS_STRIDE + k] = *(const float4*)&ve_g[(b * 64 + n0) * 256 + idx];
    }
    __syncthreads();   // B0

    float acc[4];

    // ---- stage 1: sve x w1 + ctx -> gelu -> sA
    gemm_cs(sve, w1, r, c0, acc);
    {
        float4 o = {gelu_f(acc[0] + cp1.x), gelu_f(acc[1] + cp1.y),
                    gelu_f(acc[2] + cp1.z), gelu_f(acc[3] + cp1.w)};
        *(float4*)&sA[r * LDS_STRIDE + c0] = o;
    }
    __syncthreads();   // B1

    // ---- stage 2: sA x w2 + b2 -> gelu -> sB
    gemm_cs(sA, w2, r, c0, acc);
    {
        float4 o = {gelu_f(acc[0] + bv2.x), gelu_f(acc[1] + bv2.y),
                    gelu_f(acc[2] + bv2.z), gelu_f(acc[3] + bv2.w)};
        *(float4*)&sB[r * LDS_STRIDE + c0] = o;
    }
    __syncthreads();   // B2 (also retires all sA reads -> stage 4 may overwrite sA)

    // ---- stage 3: sB x epw[0:512) + cpf -> fi (global); no barrier needed
    gemm_cs(sB, epw, r, c0, acc);
    {
        float4 o = {acc[0] + cpf.x, acc[1] + cpf.y, acc[2] + cpf.z, acc[3] + cpf.w};
        *(float4*)&fi[(b * 64 + n0 + r) * 256 + c0] = o;
    }

    // ---- stage 4: sB x epw[512:1024) + cpj -> sA -> transpose -> fjt
    gemm_cs(sB, epw + 512 * 256, r, c0, acc);
    {
        float4 o = {acc[0] + cpj.x, acc[1] + cpj.y, acc[2] + cpj.z, acc[3] + cpj.w};
        *(float4*)&sA[r * LDS_STRIDE + c0] = o;
    }
    __syncthreads();   // B3

    {
        int t = tid & 255, half = tid >> 8;
        float v0 = sA[(half * 4 + 0) * LDS_STRIDE + t];
        float v1 = sA[(half * 4 + 1) * LDS_STRIDE + t];
        float v2 = sA[(half * 4 + 2) * LDS_STRIDE + t];
        float v3 = sA[(half * 4 + 3) * LDS_STRIDE + t];
        float4 o = {v0, v1, v2, v3};
        *(float4*)&fjt[(b * 256 + t) * 64 + n0 + half * 4] = o;
    }
}

// ---------------- K3: edge logits + entropy, SPLIT BY PREDICTOR ----------------
// grid 1024: blk = (b<<5) | (ig<<1) | pred. block 512 thr = 8 waves:
// wave s = (row = s&3, dhalf = s>>2). 39KB LDS -> 4 blocks/CU.
__global__ __launch_bounds__(512) void k3_edges(
    const float* __restrict__ fi_dep, const float* __restrict__ fjt_dep,
    const float* __restrict__ fi_cep, const float* __restrict__ fjt_cep,
    const float* __restrict__ dep_w2, const float* __restrict__ dep_b2,
    const float* __restrict__ cep_w2, const float* __restrict__ cep_b2,
    float* __restrict__ Wd, float* __restrict__ Wc, float* __restrict__ entp)
{
    __shared__ float fj_s[2][64 * 64];   // 32 KB double buffer [d][j]
    __shared__ float fi_s[4][256];       // 4 KB
    __shared__ float w2_s[256];          // 1 KB
    __shared__ float red[8][64];         // 2 KB

    const int blk  = blockIdx.x;
    const int pred = blk & 1;
    const int ig   = (blk >> 1) & 15;
    const int b    = blk >> 5;
    const int tid  = threadIdx.x;
    const int s    = tid >> 6;
    const int j    = tid & 63;
    const int row  = s & 3;
    const int dh   = s >> 2;

    const float* fi_g  = pred ? fi_cep  : fi_dep;
    const float* fjt_g = pred ? fjt_cep : fjt_dep;
    const float* w2_g  = pred ? cep_w2  : dep_w2;
    const float* b2_g  = pred ? cep_b2  : dep_b2;
    float* W_out = pred ? Wc : Wd;

    if (tid < 256) {
        int rr = tid >> 6, c = (tid & 63) * 4;
        *(float4*)&fi_s[rr][c] = *(const float4*)&fi_g[(b * 64 + ig * 4 + rr) * 256 + c];
    } else if (tid < 320) {
        int t = tid - 256;
        *(float4*)&w2_s[t * 4] = *(const float4*)&w2_g[t * 4];
    }

    const float4* gF = (const float4*)(fjt_g + b * 256 * 64);

    float4 r0 = gF[tid], r1 = gF[tid + 512];
    ((float4*)fj_s[0])[tid] = r0; ((float4*)fj_s[0])[tid + 512] = r1;
    __syncthreads();

    float acc = 0.0f;
    const int d0 = dh * 32;

    #pragma unroll
    for (int c = 0; c < 4; ++c) {
        const int p = c & 1;
        if (c < 3) {
            const int off = (c + 1) * 1024;
            r0 = gF[off + tid]; r1 = gF[off + tid + 512];
        }
        const float* fj = fj_s[p];
        const int c0 = c * 64;
        #pragma unroll 4
        for (int d = d0; d < d0 + 32; d += 2) {
            float f0 = fi_s[row][c0 + d];
            float f1 = fi_s[row][c0 + d + 1];
            float g0 = fj[(d + 0) * 64 + j];
            float g1 = fj[(d + 1) * 64 + j];
            acc = fmaf(gelu_f(f0 + g0), w2_s[c0 + d],     acc);
            acc = fmaf(gelu_f(f1 + g1), w2_s[c0 + d + 1], acc);
        }
        if (c < 3) {
            const int q = p ^ 1;
            ((float4*)fj_s[q])[tid] = r0; ((float4*)fj_s[q])[tid + 512] = r1;
            __syncthreads();
        }
    }

    red[s][j] = acc;
    __syncthreads();

    if (s < 4) {
        const int i = ig * 4 + s;
        float l = (red[s][j] + red[s + 4][j]) + b2_g[0];
        if (j == i) l = -1e9f;
        W_out[(b * 64 + i) * 64 + j] = l;

        if (pred == 0) {
            float p = sigmoid_f(l);
            float e = -(p * logf(p + 1e-8f) + (1.0f - p) * logf(1.0f - p + 1e-8f));
            #pragma unroll
            for (int off = 32; off; off >>= 1) e += __shfl_down(e, off);
            if (j == 0) entp[b * 64 + i] = e;
        }
    }
}

// ---------------- K6: gate + combine + expm (PS Taylor-13, 512 thr) ----------------
__device__ __forceinline__ void mm64f2(const float* __restrict__ A, const float* __restrict__ B,
                                       int r0, int c0, float acc[2][4])
{
    #pragma unroll
    for (int i = 0; i < 2; ++i)
        #pragma unroll
        for (int j = 0; j < 4; ++j) acc[i][j] = 0.0f;
    for (int kb = 0; kb < 64; kb += 4) {
        float4 a0 = ld4(A, r0 + 0, kb);
        float4 a1 = ld4(A, r0 + 1, kb);
        #pragma unroll
        for (int kk = 0; kk < 4; ++kk) {
            float4 rv = ld4(B, kb + kk, c0);
            float x0 = f4c(a0, kk), x1 = f4c(a1, kk);
            acc[0][0] = fmaf(x0, rv.x, acc[0][0]);
            acc[0][1] = fmaf(x0, rv.y, acc[0][1]);
            acc[0][2] = fmaf(x0, rv.z, acc[0][2]);
            acc[0][3] = fmaf(x0, rv.w, acc[0][3]);
            acc[1][0] = fmaf(x1, rv.x, acc[1][0]);
            acc[1][1] = fmaf(x1, rv.y, acc[1][1]);
            acc[1][2] = fmaf(x1, rv.z, acc[1][2]);
            acc[1][3] = fmaf(x1, rv.w, acc[1][3]);
        }
    }
}

__device__ __forceinline__ void mm64d2(const float* __restrict__ A, const float* __restrict__ B,
                                       int r0, int c0, double acc[2][4])
{
    #pragma unroll
    for (int i = 0; i < 2; ++i)
        #pragma unroll
        for (int j = 0; j < 4; ++j) acc[i][j] = 0.0;
    for (int kb = 0; kb < 64; kb += 4) {
        float4 a0 = ld4(A, r0 + 0, kb);
        float4 a1 = ld4(A, r0 + 1, kb);
        #pragma unroll
        for (int kk = 0; kk < 4; ++kk) {
            float4 rv = ld4(B, kb + kk, c0);
            double rj[4] = {(double)rv.x, (double)rv.y, (double)rv.z, (double)rv.w};
            double x0 = (double)f4c(a0, kk), x1 = (double)f4c(a1, kk);
            #pragma unroll
            for (int j = 0; j < 4; ++j) {
                acc[0][j] = fma(x0, rj[j], acc[0][j]);
                acc[1][j] = fma(x1, rj[j], acc[1][j]);
            }
        }
    }
}

__global__ __launch_bounds__(512) void k6_gate_expm(
    const float* __restrict__ Wd, const float* __restrict__ Wc,
    const float* __restrict__ entp,
    const float* __restrict__ gw1, const float* __restrict__ gb1,
    const float* __restrict__ gw2, const float* __restrict__ gb2,
    const int* __restrict__ n_samples,
    float* __restrict__ out, float* __restrict__ traces)
{
    __shared__ float Xs [64 * ES];
    __shared__ float X2s[64 * ES];
    __shared__ float X3s[64 * ES];
    __shared__ float Ra [64 * ES];
    __shared__ float Rb [64 * ES];
    __shared__ float sgate;
    __shared__ float sent;
    __shared__ int ssexp;

    const int b = blockIdx.x;
    const int tid = threadIdx.x;

    const float C2 = 0.5f, C3 = 1.0f/6.0f, C4 = 1.0f/24.0f, C5 = 1.0f/120.0f;
    const float C6 = 1.0f/720.0f, C7 = 1.0f/5040.0f, C8 = 1.0f/40320.0f;
    const float C9 = 1.0f/362880.0f, C10 = 1.0f/3628800.0f, C11 = 1.0f/39916800.0f;
    const float C12 = 1.0f/479001600.0f, C13 = 1.0f/6227020800.0f;

    if (tid < 64) {
        float v = entp[b * 64 + tid];
        #pragma unroll
        for (int off = 32; off; off >>= 1) v += __shfl_down(v, off);
        if (tid == 0) sent = v / 4096.0f;
    }
    __syncthreads();
    if (tid < 64) {
        float ns = fminf((float)n_samples[0] / 1000.0f, 1.0f);
        float ccf = 0.5f;
        float pre = ns * gw1[tid] + ccf * gw1[64 + tid] + sent * gw1[128 + tid] + gb1[tid];
        float hid = gelu_f(pre) * gw2[tid];
        #pragma unroll
        for (int off = 32; off; off >>= 1) hid += __shfl_down(hid, off);
        if (tid == 0) sgate = sigmoid_f(hid + gb2[0]);
    }
    __syncthreads();
    const float g = sgate;

    for (int idx = tid; idx < 4096; idx += 512) {
        float d = Wd[b * 4096 + idx];
        float c = Wc[b * 4096 + idx];
        float post = g * d + (1.0f - g) * c;
        float sg = sigmoid_f(post);
        out[b * 4096 + idx] = sg;
        Xs[(idx >> 6) * ES + (idx & 63)] = sg * sg;
    }
    __syncthreads();

    if (tid < 64) {
        float cs = 0.0f;
        for (int r = 0; r < 64; ++r) cs += Xs[r * ES + tid];
        #pragma unroll
        for (int off = 32; off; off >>= 1) cs = fmaxf(cs, __shfl_down(cs, off));
        if (tid == 0) {
            int se = 0;
            if (cs > 2.0f) se = (int)ceilf(log2f(cs * 0.5f));
            if (se < 0) se = 0;
            if (se > 12) se = 12;
            ssexp = se;
        }
    }
    __syncthreads();
    const int sexp = ssexp;
    const float scale = ldexpf(1.0f, -sexp);
    for (int idx = tid; idx < 4096; idx += 512) {
        Xs[(idx >> 6) * ES + (idx & 63)] *= scale;
    }
    __syncthreads();

    const int r0 = (tid >> 4) * 2;
    const int c0 = (tid & 15) * 4;
    float acc[2][4];

    // mm1: X2 = X*X
    mm64f2(Xs, Xs, r0, c0, acc);
    #pragma unroll
    for (int i = 0; i < 2; ++i) {
        float4 o = {acc[i][0], acc[i][1], acc[i][2], acc[i][3]};
        *(float4*)&X2s[(r0 + i) * ES + c0] = o;
    }
    __syncthreads();

    // mm2: X3 = X2*X
    mm64f2(X2s, Xs, r0, c0, acc);
    #pragma unroll
    for (int i = 0; i < 2; ++i) {
        float4 o = {acc[i][0], acc[i][1], acc[i][2], acc[i][3]};
        *(float4*)&X3s[(r0 + i) * ES + c0] = o;
    }
    __syncthreads();

    // mm3: Ra = C13*(X*X3) + C12*X3 + C11*X2 + C10*X + C9*I
    mm64f2(Xs, X3s, r0, c0, acc);
    #pragma unroll
    for (int i = 0; i < 2; ++i) {
        float4 xv = ld4(Xs, r0 + i, c0);
        float4 x2 = ld4(X2s, r0 + i, c0);
        float4 x3 = ld4(X3s, r0 + i, c0);
        float o[4];
        #pragma unroll
        for (int j = 0; j < 4; ++j) {
            o[j] = C13 * acc[i][j] + C12 * f4c(x3, j) + C10 * f4c(xv, j) + C11 * f4c(x2, j)
                 + ((r0 + i) == (c0 + j) ? C9 : 0.0f);
        }
        float4 ov = {o[0], o[1], o[2], o[3]};
        *(float4*)&Ra[(r0 + i) * ES + c0] = ov;
    }
    __syncthreads();

    // mm4: Rb = Ra*Y + B2
    mm64f2(Ra, X3s, r0, c0, acc);
    #pragma unroll
    for (int i = 0; i < 2; ++i) {
        float4 xv = ld4(Xs, r0 + i, c0);
        float4 x2 = ld4(X2s, r0 + i, c0);
        float o[4];
        #pragma unroll
        for (int j = 0; j < 4; ++j) {
            o[j] = acc[i][j] + C7 * f4c(xv, j) + C8 * f4c(x2, j)
                 + ((r0 + i) == (c0 + j) ? C6 : 0.0f);
        }
        float4 ov = {o[0], o[1], o[2], o[3]};
        *(float4*)&Rb[(r0 + i) * ES + c0] = ov;
    }
    __syncthreads();

    // mm5: Ra = Rb*Y + B1
    mm64f2(Rb, X3s, r0, c0, acc);
    #pragma unroll
    for (int i = 0; i < 2; ++i) {
        float4 xv = ld4(Xs, r0 + i, c0);
        float4 x2 = ld4(X2s, r0 + i, c0);
        float o[4];
        #pragma unroll
        for (int j = 0; j < 4; ++j) {
            o[j] = acc[i][j] + C4 * f4c(xv, j) + C5 * f4c(x2, j)
                 + ((r0 + i) == (c0 + j) ? C3 : 0.0f);
        }
        float4 ov = {o[0], o[1], o[2], o[3]};
        *(float4*)&Ra[(r0 + i) * ES + c0] = ov;
    }
    __syncthreads();

    // mm6: Rb = Ra*Y + B0
    mm64f2(Ra, X3s, r0, c0, acc);
    #pragma unroll
    for (int i = 0; i < 2; ++i) {
        float4 xv = ld4(Xs, r0 + i, c0);
        float4 x2 = ld4(X2s, r0 + i, c0);
        float o[4];
        #pragma unroll
        for (int j = 0; j < 4; ++j) {
            o[j] = acc[i][j] + f4c(xv, j) + C2 * f4c(x2, j)
                 + ((r0 + i) == (c0 + j) ? 1.0f : 0.0f);
        }
        float4 ov = {o[0], o[1], o[2], o[3]};
        *(float4*)&Rb[(r0 + i) * ES + c0] = ov;
    }
    __syncthreads();

    float* cur = Rb;
    float* oth = Ra;
    for (int sq = 0; sq < sexp; ++sq) {
        double dacc[2][4];
        mm64d2(cur, cur, r0, c0, dacc);
        #pragma unroll
        for (int i = 0; i < 2; ++i) {
            float4 o = {(float)dacc[i][0], (float)dacc[i][1], (float)dacc[i][2], (float)dacc[i][3]};
            *(float4*)&oth[(r0 + i) * ES + c0] = o;
        }
        __syncthreads();
        float* t = cur; cur = oth; oth = t;
    }

    if (tid < 64) {
        double v = (double)cur[tid * ES + tid];
        #pragma unroll
        for (int off = 32; off; off >>= 1) v += __shfl_down(v, off);
        if (tid == 0) traces[b] = (float)v;
    }
}

// ---------------- K7: acyc ----------------
__global__ void k7_acyc(const float* __restrict__ traces, float* __restrict__ out)
{
    if (threadIdx.x == 0 && blockIdx.x == 0) {
        double s = 0.0;
        for (int b = 0; b < 32; ++b) s += (double)traces[b];
        out[131072] = (float)(s / 32.0 - 64.0);
    }
}

extern "C" void kernel_launch(void* const* d_in, const int* in_sizes, int n_in,
                              void* d_out, int out_size, void* d_ws, size_t ws_size,
                              hipStream_t stream)
{
    (void)in_sizes; (void)n_in; (void)out_size; (void)ws_size;

    const float* ds     = (const float*)d_in[0];
    const float* ve     = (const float*)d_in[1];
    const float* cc     = (const float*)d_in[2];
    const float* dge_w1 = (const float*)d_in[3];
    const float* dge_b1 = (const float*)d_in[4];
    const float* dge_w2 = (const float*)d_in[5];
    const float* dge_b2 = (const float*)d_in[6];
    const float* cge_w1 = (const float*)d_in[7];
    const float* cge_b1 = (const float*)d_in[8];
    const float* cge_w2 = (const float*)d_in[9];
    const float* cge_b2 = (const float*)d_in[10];
    const float* dep_w1 = (const float*)d_in[11];
    const float* dep_b1 = (const float*)d_in[12];
    const float* dep_w2 = (const float*)d_in[13];
    const float* dep_b2 = (const float*)d_in[14];
    const float* cep_w1 = (const float*)d_in[15];
    const float* cep_b1 = (const float*)d_in[16];
    const float* cep_w2 = (const float*)d_in[17];
    const float* cep_b2 = (const float*)d_in[18];
    const float* gw1    = (const float*)d_in[19];
    const float* gb1    = (const float*)d_in[20];
    const float* gw2    = (const float*)d_in[21];
    const float* gb2    = (const float*)d_in[22];
    const int*   nsamp  = (const int*)d_in[23];

    float* ws = (float*)d_ws;
    float* ctxproj = ws;                       // 6*32*256   = 49152
    float* fi_dep  = ctxproj + 49152;          // 32*64*256  = 524288
    float* fjt_dep = fi_dep + 524288;          // 524288
    float* fi_cep  = fjt_dep + 524288;         // 524288
    float* fjt_cep = fi_cep + 524288;          // 524288
    float* Wd      = fjt_cep + 524288;         // 131072
    float* Wc      = Wd + 131072;              // 131072
    float* entp    = Wc + 131072;              // 2048
    float* traces  = entp + 2048;              // 32

    float* outp = (float*)d_out;

    k0_ctx<<<dim3(32, 6), 256, 0, stream>>>(ds, cc, dge_w1, dge_b1, cge_w1, cge_b1,
                                            dep_w1, dep_b1, cep_w1, cep_b1, ctxproj);
    k1_encode<<<512, 512, 0, stream>>>(ve, dge_w1, dge_w2, dge_b2,
                                       cge_w1, cge_w2, cge_b2,
                                       dep_w1, cep_w1, ctxproj,
                                       fi_dep, fjt_dep, fi_cep, fjt_cep);
    k3_edges<<<1024, 512, 0, stream>>>(fi_dep, fjt_dep, fi_cep, fjt_cep,
                                       dep_w2, dep_b2, cep_w2, cep_b2,
                                       Wd, Wc, entp);
    k6_gate_expm<<<32, 512, 0, stream>>>(Wd, Wc, entp, gw1, gb1, gw2, gb2,
                                         nsamp, outp, traces);
    k7_acyc<<<1, 64, 0, stream>>>(traces, outp);
}

// Round 12
// 120.360 us; speedup vs baseline: 1.6928x; 1.6928x over previous
//
#include <hip/hip_runtime.h>
#include <hip/hip_bf16.h>

// GraphPosteriorHead: B=32, N=64, D=256
// Pipeline:
//  K0: ctx projections (6x (32,256))       -> ws
//  K1: split encoder chains; k-split-8, paired-wave RMW part reduce (REVERTED
//      r10 version — col-split r11 was VMEM-issue-bound: 8x W-load instrs at
//      128B/wave. k1 needs row-reuse + lane-spanning W cols simultaneously.)
//  K3: edge logits + entropy; split by predictor, dbuf fjt staging
//  K6: gate + combine + W_posterior + expm; 512 thr, PS Taylor-13, thr 2.0
//  K7: acyc reduction -> out[131072]

#define LDS_STRIDE 260   // 256 + 4 pad
#define ES 68            // expm LDS row stride

// Branch-free gelu: erf via Abramowitz-Stegun 7.1.26 (|abs err| <= 1.5e-7).
// Uses v_rcp_f32: a precise 1.0f/x lowers to the ~11-op div sequence (r6 lesson).
__device__ __forceinline__ float gelu_f(float x) {
    float z = fabsf(x) * 0.70710678118654752440f;
    float t = __builtin_amdgcn_rcpf(fmaf(0.3275911f, z, 1.0f));
    float p = t * fmaf(t, fmaf(t, fmaf(t, fmaf(t, 1.061405429f, -1.453152027f),
                                       1.421413741f), -0.284496736f), 0.254829592f);
    float e = __expf(-z * z);
    float erfv = fmaf(-p, e, 1.0f);
    erfv = copysignf(erfv, x);
    return 0.5f * x * (1.0f + erfv);
}
__device__ __forceinline__ float sigmoid_f(float x) {
    return 1.0f / (1.0f + expf(-x));
}
__device__ __forceinline__ float f4c(const float4& v, int k) {
    return k == 0 ? v.x : k == 1 ? v.y : k == 2 ? v.z : v.w;
}
__device__ __forceinline__ float4 ld4(const float* __restrict__ buf, int r, int c) {
    return *(const float4*)&buf[r * ES + c];
}

// ---------------- K0: context projections ----------------
__global__ __launch_bounds__(256) void k0_ctx(
    const float* __restrict__ ds, const float* __restrict__ cc,
    const float* __restrict__ dge_w1, const float* __restrict__ dge_b1,
    const float* __restrict__ cge_w1, const float* __restrict__ cge_b1,
    const float* __restrict__ dep_w1, const float* __restrict__ dep_b1,
    const float* __restrict__ cep_w1, const float* __restrict__ cep_b1,
    float* __restrict__ ctxproj)
{
    const int b = blockIdx.x;
    const int which = blockIdx.y;
    const float* ctx; const float* W; const float* bias;
    switch (which) {
        case 0:  ctx = ds; W = dge_w1 + 256 * 256; bias = dge_b1; break;
        case 1:  ctx = cc; W = cge_w1 + 256 * 256; bias = cge_b1; break;
        case 2:  ctx = ds; W = dep_w1 + 256 * 256; bias = dep_b1; break;
        case 3:  ctx = ds; W = dep_w1 + 768 * 256; bias = nullptr; break;
        case 4:  ctx = cc; W = cep_w1 + 256 * 256; bias = cep_b1; break;
        default: ctx = cc; W = cep_w1 + 768 * 256; bias = nullptr; break;
    }
    __shared__ float sctx[256];
    const int tid = threadIdx.x;
    sctx[tid] = ctx[b * 256 + tid];
    __syncthreads();
    float acc = 0.0f;
    #pragma unroll 2
    for (int k = 0; k < 256; k += 4) {
        float4 c4 = *(const float4*)&sctx[k];
        acc = fmaf(c4.x, W[(k + 0) * 256 + tid], acc);
        acc = fmaf(c4.y, W[(k + 1) * 256 + tid], acc);
        acc = fmaf(c4.z, W[(k + 2) * 256 + tid], acc);
        acc = fmaf(c4.w, W[(k + 3) * 256 + tid], acc);
    }
    if (bias) acc += bias[tid];
    ctxproj[(which * 32 + b) * 256 + tid] = acc;
}

// ---------------- K1: split encoder chains (k-split-8, RMW reduce) ----------------
__device__ __forceinline__ void gemm_ks(const float* __restrict__ src,
                                        const float* __restrict__ W,
                                        int ks0, int t0, float acc[8][4])
{
    #pragma unroll
    for (int r = 0; r < 8; ++r)
        #pragma unroll
        for (int c = 0; c < 4; ++c) acc[r][c] = 0.0f;
    #pragma unroll 2
    for (int k = ks0; k < ks0 + 32; k += 4) {
        float4 wv0 = *(const float4*)&W[(k + 0) * 256 + t0];
        float4 wv1 = *(const float4*)&W[(k + 1) * 256 + t0];
        float4 wv2 = *(const float4*)&W[(k + 2) * 256 + t0];
        float4 wv3 = *(const float4*)&W[(k + 3) * 256 + t0];
        float4 a[8];
        #pragma unroll
        for (int r = 0; r < 8; ++r) a[r] = *(const float4*)&src[r * LDS_STRIDE + k];
        float4 wvs[4] = {wv0, wv1, wv2, wv3};
        #pragma unroll
        for (int kk = 0; kk < 4; ++kk) {
            float4 wv = wvs[kk];
            #pragma unroll
            for (int r = 0; r < 8; ++r) {
                float av = f4c(a[r], kk);
                acc[r][0] = fmaf(av, wv.x, acc[r][0]);
                acc[r][1] = fmaf(av, wv.y, acc[r][1]);
                acc[r][2] = fmaf(av, wv.z, acc[r][2]);
                acc[r][3] = fmaf(av, wv.w, acc[r][3]);
            }
        }
    }
}

// paired-wave reduction: waves 0-3 write slots 0-3; sync; waves 4-7 accumulate
// into slot (w-4); sync. part = [4][8][256] = 32KB.
__device__ __forceinline__ void part_write_rmw(float* __restrict__ part, int w, int t0,
                                               const float acc[8][4])
{
    if (w < 4) {
        #pragma unroll
        for (int r = 0; r < 8; ++r) {
            float4 o = {acc[r][0], acc[r][1], acc[r][2], acc[r][3]};
            *(float4*)&part[(w * 8 + r) * 256 + t0] = o;
        }
    }
    __syncthreads();
    if (w >= 4) {
        #pragma unroll
        for (int r = 0; r < 8; ++r) {
            float4 v = *(const float4*)&part[((w - 4) * 8 + r) * 256 + t0];
            float4 o = {v.x + acc[r][0], v.y + acc[r][1], v.z + acc[r][2], v.w + acc[r][3]};
            *(float4*)&part[((w - 4) * 8 + r) * 256 + t0] = o;
        }
    }
    __syncthreads();
}

__device__ __forceinline__ float4 reduce4(const float* __restrict__ part, int r, int t0)
{
    float4 s = {0.0f, 0.0f, 0.0f, 0.0f};
    #pragma unroll
    for (int sl = 0; sl < 4; ++sl) {
        float4 v = *(const float4*)&part[(sl * 8 + r) * 256 + t0];
        s.x += v.x; s.y += v.y; s.z += v.z; s.w += v.w;
    }
    return s;
}

// grid 512: blk = (((b*8)+chunk)*2)+chain. chain 0 = dge->dep, 1 = cge->cep.
__global__ __launch_bounds__(512, 4) void k1_encode(
    const float* __restrict__ ve_g,
    const float* __restrict__ dge_w1, const float* __restrict__ dge_w2, const float* __restrict__ dge_b2,
    const float* __restrict__ cge_w1, const float* __restrict__ cge_w2, const float* __restrict__ cge_b2,
    const float* __restrict__ dep_w1, const float* __restrict__ cep_w1,
    const float* __restrict__ ctxproj,
    float* __restrict__ fi_dep, float* __restrict__ fjt_dep,
    float* __restrict__ fi_cep, float* __restrict__ fjt_cep)
{
    __shared__ float sve[8 * LDS_STRIDE];
    __shared__ float sA[8 * LDS_STRIDE];
    __shared__ float sB[8 * LDS_STRIDE];
    __shared__ float part[4 * 8 * 256];   // 32 KB

    const int tid   = threadIdx.x;
    const int blk   = blockIdx.x;
    const int chain = blk & 1;
    const int chunk = (blk >> 1) & 7;
    const int b     = blk >> 4;
    const int n0    = chunk * 8;

    const float* w1   = chain ? cge_w1 : dge_w1;
    const float* w2   = chain ? cge_w2 : dge_w2;
    const float* b2   = chain ? cge_b2 : dge_b2;
    const float* epw  = chain ? cep_w1 : dep_w1;
    float* fi  = chain ? fi_cep  : fi_dep;
    float* fjt = chain ? fjt_cep : fjt_dep;
    const int cp_s1 = chain ? 1 : 0;
    const int cp_fi = chain ? 4 : 2;
    const int cp_fj = chain ? 5 : 3;

    const int w  = tid >> 6;
    const int t0 = (tid & 63) * 4;
    const int ks0 = w * 32;

    float4 cp1 = *(const float4*)&ctxproj[(cp_s1 * 32 + b) * 256 + t0];
    float4 bv2 = *(const float4*)&b2[t0];
    float4 cpf = *(const float4*)&ctxproj[(cp_fi * 32 + b) * 256 + t0];
    float4 cpj = *(const float4*)&ctxproj[(cp_fj * 32 + b) * 256 + t0];

    {
        int idx = tid * 4;
        int r = idx >> 8, k = idx & 255;
        *(float4*)&sve[r * LDS_STRIDE + k] = *(const float4*)&ve_g[(b * 64 + n0) * 256 + idx];
    }
    __syncthreads();

    float acc[8][4];

    // ---- stage 1: sve x w1 + ctx -> gelu -> sA
    gemm_ks(sve, w1, ks0, t0, acc);
    part_write_rmw(part, w, t0, acc);
    {
        float4 s = reduce4(part, w, t0);
        float4 o = {gelu_f(s.x + cp1.x), gelu_f(s.y + cp1.y),
                    gelu_f(s.z + cp1.z), gelu_f(s.w + cp1.w)};
        *(float4*)&sA[w * LDS_STRIDE + t0] = o;
    }
    __syncthreads();

    // ---- stage 2: sA x w2 + b2 -> gelu -> sB
    gemm_ks(sA, w2, ks0, t0, acc);
    part_write_rmw(part, w, t0, acc);
    {
        float4 s = reduce4(part, w, t0);
        float4 o = {gelu_f(s.x + bv2.x), gelu_f(s.y + bv2.y),
                    gelu_f(s.z + bv2.z), gelu_f(s.w + bv2.w)};
        *(float4*)&sB[w * LDS_STRIDE + t0] = o;
    }
    __syncthreads();

    // ---- stage 3: sB x epw[0:512) + cpf -> fi (global)
    gemm_ks(sB, epw, ks0, t0, acc);
    part_write_rmw(part, w, t0, acc);
    {
        float4 s = reduce4(part, w, t0);
        float4 o = {s.x + cpf.x, s.y + cpf.y, s.z + cpf.z, s.w + cpf.w};
        *(float4*)&fi[(b * 64 + n0 + w) * 256 + t0] = o;
    }
    __syncthreads();

    // ---- stage 4: sB x epw[512:1024) + cpj -> sA -> transpose -> fjt
    gemm_ks(sB, epw + 512 * 256, ks0, t0, acc);
    part_write_rmw(part, w, t0, acc);
    {
        float4 s = reduce4(part, w, t0);
        float4 o = {s.x + cpj.x, s.y + cpj.y, s.z + cpj.z, s.w + cpj.w};
        *(float4*)&sA[w * LDS_STRIDE + t0] = o;
    }
    __syncthreads();
    {
        int t = tid & 255, half = tid >> 8;
        float v0 = sA[(half * 4 + 0) * LDS_STRIDE + t];
        float v1 = sA[(half * 4 + 1) * LDS_STRIDE + t];
        float v2 = sA[(half * 4 + 2) * LDS_STRIDE + t];
        float v3 = sA[(half * 4 + 3) * LDS_STRIDE + t];
        float4 o = {v0, v1, v2, v3};
        *(float4*)&fjt[(b * 256 + t) * 64 + n0 + half * 4] = o;
    }
}

// ---------------- K3: edge logits + entropy, SPLIT BY PREDICTOR ----------------
// grid 1024: blk = (b<<5) | (ig<<1) | pred. block 512 thr = 8 waves:
// wave s = (row = s&3, dhalf = s>>2). 39KB LDS -> 4 blocks/CU.
__global__ __launch_bounds__(512) void k3_edges(
    const float* __restrict__ fi_dep, const float* __restrict__ fjt_dep,
    const float* __restrict__ fi_cep, const float* __restrict__ fjt_cep,
    const float* __restrict__ dep_w2, const float* __restrict__ dep_b2,
    const float* __restrict__ cep_w2, const float* __restrict__ cep_b2,
    float* __restrict__ Wd, float* __restrict__ Wc, float* __restrict__ entp)
{
    __shared__ float fj_s[2][64 * 64];   // 32 KB double buffer [d][j]
    __shared__ float fi_s[4][256];       // 4 KB
    __shared__ float w2_s[256];          // 1 KB
    __shared__ float red[8][64];         // 2 KB

    const int blk  = blockIdx.x;
    const int pred = blk & 1;
    const int ig   = (blk >> 1) & 15;
    const int b    = blk >> 5;
    const int tid  = threadIdx.x;
    const int s    = tid >> 6;
    const int j    = tid & 63;
    const int row  = s & 3;
    const int dh   = s >> 2;

    const float* fi_g  = pred ? fi_cep  : fi_dep;
    const float* fjt_g = pred ? fjt_cep : fjt_dep;
    const float* w2_g  = pred ? cep_w2  : dep_w2;
    const float* b2_g  = pred ? cep_b2  : dep_b2;
    float* W_out = pred ? Wc : Wd;

    if (tid < 256) {
        int rr = tid >> 6, c = (tid & 63) * 4;
        *(float4*)&fi_s[rr][c] = *(const float4*)&fi_g[(b * 64 + ig * 4 + rr) * 256 + c];
    } else if (tid < 320) {
        int t = tid - 256;
        *(float4*)&w2_s[t * 4] = *(const float4*)&w2_g[t * 4];
    }

    const float4* gF = (const float4*)(fjt_g + b * 256 * 64);

    float4 r0 = gF[tid], r1 = gF[tid + 512];
    ((float4*)fj_s[0])[tid] = r0; ((float4*)fj_s[0])[tid + 512] = r1;
    __syncthreads();

    float acc = 0.0f;
    const int d0 = dh * 32;

    #pragma unroll
    for (int c = 0; c < 4; ++c) {
        const int p = c & 1;
        if (c < 3) {
            const int off = (c + 1) * 1024;
            r0 = gF[off + tid]; r1 = gF[off + tid + 512];
        }
        const float* fj = fj_s[p];
        const int c0 = c * 64;
        #pragma unroll 4
        for (int d = d0; d < d0 + 32; d += 2) {
            float f0 = fi_s[row][c0 + d];
            float f1 = fi_s[row][c0 + d + 1];
            float g0 = fj[(d + 0) * 64 + j];
            float g1 = fj[(d + 1) * 64 + j];
            acc = fmaf(gelu_f(f0 + g0), w2_s[c0 + d],     acc);
            acc = fmaf(gelu_f(f1 + g1), w2_s[c0 + d + 1], acc);
        }
        if (c < 3) {
            const int q = p ^ 1;
            ((float4*)fj_s[q])[tid] = r0; ((float4*)fj_s[q])[tid + 512] = r1;
            __syncthreads();
        }
    }

    red[s][j] = acc;
    __syncthreads();

    if (s < 4) {
        const int i = ig * 4 + s;
        float l = (red[s][j] + red[s + 4][j]) + b2_g[0];
        if (j == i) l = -1e9f;
        W_out[(b * 64 + i) * 64 + j] = l;

        if (pred == 0) {
            float p = sigmoid_f(l);
            float e = -(p * logf(p + 1e-8f) + (1.0f - p) * logf(1.0f - p + 1e-8f));
            #pragma unroll
            for (int off = 32; off; off >>= 1) e += __shfl_down(e, off);
            if (j == 0) entp[b * 64 + i] = e;
        }
    }
}

// ---------------- K6: gate + combine + expm (PS Taylor-13, 512 thr) ----------------
__device__ __forceinline__ void mm64f2(const float* __restrict__ A, const float* __restrict__ B,
                                       int r0, int c0, float acc[2][4])
{
    #pragma unroll
    for (int i = 0; i < 2; ++i)
        #pragma unroll
        for (int j = 0; j < 4; ++j) acc[i][j] = 0.0f;
    for (int kb = 0; kb < 64; kb += 4) {
        float4 a0 = ld4(A, r0 + 0, kb);
        float4 a1 = ld4(A, r0 + 1, kb);
        #pragma unroll
        for (int kk = 0; kk < 4; ++kk) {
            float4 rv = ld4(B, kb + kk, c0);
            float x0 = f4c(a0, kk), x1 = f4c(a1, kk);
            acc[0][0] = fmaf(x0, rv.x, acc[0][0]);
            acc[0][1] = fmaf(x0, rv.y, acc[0][1]);
            acc[0][2] = fmaf(x0, rv.z, acc[0][2]);
            acc[0][3] = fmaf(x0, rv.w, acc[0][3]);
            acc[1][0] = fmaf(x1, rv.x, acc[1][0]);
            acc[1][1] = fmaf(x1, rv.y, acc[1][1]);
            acc[1][2] = fmaf(x1, rv.z, acc[1][2]);
            acc[1][3] = fmaf(x1, rv.w, acc[1][3]);
        }
    }
}

__device__ __forceinline__ void mm64d2(const float* __restrict__ A, const float* __restrict__ B,
                                       int r0, int c0, double acc[2][4])
{
    #pragma unroll
    for (int i = 0; i < 2; ++i)
        #pragma unroll
        for (int j = 0; j < 4; ++j) acc[i][j] = 0.0;
    for (int kb = 0; kb < 64; kb += 4) {
        float4 a0 = ld4(A, r0 + 0, kb);
        float4 a1 = ld4(A, r0 + 1, kb);
        #pragma unroll
        for (int kk = 0; kk < 4; ++kk) {
            float4 rv = ld4(B, kb + kk, c0);
            double rj[4] = {(double)rv.x, (double)rv.y, (double)rv.z, (double)rv.w};
            double x0 = (double)f4c(a0, kk), x1 = (double)f4c(a1, kk);
            #pragma unroll
            for (int j = 0; j < 4; ++j) {
                acc[0][j] = fma(x0, rj[j], acc[0][j]);
                acc[1][j] = fma(x1, rj[j], acc[1][j]);
            }
        }
    }
}

__global__ __launch_bounds__(512) void k6_gate_expm(
    const float* __restrict__ Wd, const float* __restrict__ Wc,
    const float* __restrict__ entp,
    const float* __restrict__ gw1, const float* __restrict__ gb1,
    const float* __restrict__ gw2, const float* __restrict__ gb2,
    const int* __restrict__ n_samples,
    float* __restrict__ out, float* __restrict__ traces)
{
    __shared__ float Xs [64 * ES];
    __shared__ float X2s[64 * ES];
    __shared__ float X3s[64 * ES];
    __shared__ float Ra [64 * ES];
    __shared__ float Rb [64 * ES];
    __shared__ float sgate;
    __shared__ float sent;
    __shared__ int ssexp;

    const int b = blockIdx.x;
    const int tid = threadIdx.x;

    const float C2 = 0.5f, C3 = 1.0f/6.0f, C4 = 1.0f/24.0f, C5 = 1.0f/120.0f;
    const float C6 = 1.0f/720.0f, C7 = 1.0f/5040.0f, C8 = 1.0f/40320.0f;
    const float C9 = 1.0f/362880.0f, C10 = 1.0f/3628800.0f, C11 = 1.0f/39916800.0f;
    const float C12 = 1.0f/479001600.0f, C13 = 1.0f/6227020800.0f;

    if (tid < 64) {
        float v = entp[b * 64 + tid];
        #pragma unroll
        for (int off = 32; off; off >>= 1) v += __shfl_down(v, off);
        if (tid == 0) sent = v / 4096.0f;
    }
    __syncthreads();
    if (tid < 64) {
        float ns = fminf((float)n_samples[0] / 1000.0f, 1.0f);
        float ccf = 0.5f;
        float pre = ns * gw1[tid] + ccf * gw1[64 + tid] + sent * gw1[128 + tid] + gb1[tid];
        float hid = gelu_f(pre) * gw2[tid];
        #pragma unroll
        for (int off = 32; off; off >>= 1) hid += __shfl_down(hid, off);
        if (tid == 0) sgate = sigmoid_f(hid + gb2[0]);
    }
    __syncthreads();
    const float g = sgate;

    for (int idx = tid; idx < 4096; idx += 512) {
        float d = Wd[b * 4096 + idx];
        float c = Wc[b * 4096 + idx];
        float post = g * d + (1.0f - g) * c;
        float sg = sigmoid_f(post);
        out[b * 4096 + idx] = sg;
        Xs[(idx >> 6) * ES + (idx & 63)] = sg * sg;
    }
    __syncthreads();

    if (tid < 64) {
        float cs = 0.0f;
        for (int r = 0; r < 64; ++r) cs += Xs[r * ES + tid];
        #pragma unroll
        for (int off = 32; off; off >>= 1) cs = fmaxf(cs, __shfl_down(cs, off));
        if (tid == 0) {
            int se = 0;
            if (cs > 2.0f) se = (int)ceilf(log2f(cs * 0.5f));
            if (se < 0) se = 0;
            if (se > 12) se = 12;
            ssexp = se;
        }
    }
    __syncthreads();
    const int sexp = ssexp;
    const float scale = ldexpf(1.0f, -sexp);
    for (int idx = tid; idx < 4096; idx += 512) {
        Xs[(idx >> 6) * ES + (idx & 63)] *= scale;
    }
    __syncthreads();

    const int r0 = (tid >> 4) * 2;
    const int c0 = (tid & 15) * 4;
    float acc[2][4];

    // mm1: X2 = X*X
    mm64f2(Xs, Xs, r0, c0, acc);
    #pragma unroll
    for (int i = 0; i < 2; ++i) {
        float4 o = {acc[i][0], acc[i][1], acc[i][2], acc[i][3]};
        *(float4*)&X2s[(r0 + i) * ES + c0] = o;
    }
    __syncthreads();

    // mm2: X3 = X2*X
    mm64f2(X2s, Xs, r0, c0, acc);
    #pragma unroll
    for (int i = 0; i < 2; ++i) {
        float4 o = {acc[i][0], acc[i][1], acc[i][2], acc[i][3]};
        *(float4*)&X3s[(r0 + i) * ES + c0] = o;
    }
    __syncthreads();

    // mm3: Ra = C13*(X*X3) + C12*X3 + C11*X2 + C10*X + C9*I
    mm64f2(Xs, X3s, r0, c0, acc);
    #pragma unroll
    for (int i = 0; i < 2; ++i) {
        float4 xv = ld4(Xs, r0 + i, c0);
        float4 x2 = ld4(X2s, r0 + i, c0);
        float4 x3 = ld4(X3s, r0 + i, c0);
        float o[4];
        #pragma unroll
        for (int j = 0; j < 4; ++j) {
            o[j] = C13 * acc[i][j] + C12 * f4c(x3, j) + C10 * f4c(xv, j) + C11 * f4c(x2, j)
                 + ((r0 + i) == (c0 + j) ? C9 : 0.0f);
        }
        float4 ov = {o[0], o[1], o[2], o[3]};
        *(float4*)&Ra[(r0 + i) * ES + c0] = ov;
    }
    __syncthreads();

    // mm4: Rb = Ra*Y + B2
    mm64f2(Ra, X3s, r0, c0, acc);
    #pragma unroll
    for (int i = 0; i < 2; ++i) {
        float4 xv = ld4(Xs, r0 + i, c0);
        float4 x2 = ld4(X2s, r0 + i, c0);
        float o[4];
        #pragma unroll
        for (int j = 0; j < 4; ++j) {
            o[j] = acc[i][j] + C7 * f4c(xv, j) + C8 * f4c(x2, j)
                 + ((r0 + i) == (c0 + j) ? C6 : 0.0f);
        }
        float4 ov = {o[0], o[1], o[2], o[3]};
        *(float4*)&Rb[(r0 + i) * ES + c0] = ov;
    }
    __syncthreads();

    // mm5: Ra = Rb*Y + B1
    mm64f2(Rb, X3s, r0, c0, acc);
    #pragma unroll
    for (int i = 0; i < 2; ++i) {
        float4 xv = ld4(Xs, r0 + i, c0);
        float4 x2 = ld4(X2s, r0 + i, c0);
        float o[4];
        #pragma unroll
        for (int j = 0; j < 4; ++j) {
            o[j] = acc[i][j] + C4 * f4c(xv, j) + C5 * f4c(x2, j)
                 + ((r0 + i) == (c0 + j) ? C3 : 0.0f);
        }
        float4 ov = {o[0], o[1], o[2], o[3]};
        *(float4*)&Ra[(r0 + i) * ES + c0] = ov;
    }
    __syncthreads();

    // mm6: Rb = Ra*Y + B0
    mm64f2(Ra, X3s, r0, c0, acc);
    #pragma unroll
    for (int i = 0; i < 2; ++i) {
        float4 xv = ld4(Xs, r0 + i, c0);
        float4 x2 = ld4(X2s, r0 + i, c0);
        float o[4];
        #pragma unroll
        for (int j = 0; j < 4; ++j) {
            o[j] = acc[i][j] + f4c(xv, j) + C2 * f4c(x2, j)
                 + ((r0 + i) == (c0 + j) ? 1.0f : 0.0f);
        }
        float4 ov = {o[0], o[1], o[2], o[3]};
        *(float4*)&Rb[(r0 + i) * ES + c0] = ov;
    }
    __syncthreads();

    float* cur = Rb;
    float* oth = Ra;
    for (int sq = 0; sq < sexp; ++sq) {
        double dacc[2][4];
        mm64d2(cur, cur, r0, c0, dacc);
        #pragma unroll
        for (int i = 0; i < 2; ++i) {
            float4 o = {(float)dacc[i][0], (float)dacc[i][1], (float)dacc[i][2], (float)dacc[i][3]};
            *(float4*)&oth[(r0 + i) * ES + c0] = o;
        }
        __syncthreads();
        float* t = cur; cur = oth; oth = t;
    }

    if (tid < 64) {
        double v = (double)cur[tid * ES + tid];
        #pragma unroll
        for (int off = 32; off; off >>= 1) v += __shfl_down(v, off);
        if (tid == 0) traces[b] = (float)v;
    }
}

// ---------------- K7: acyc ----------------
__global__ void k7_acyc(const float* __restrict__ traces, float* __restrict__ out)
{
    if (threadIdx.x == 0 && blockIdx.x == 0) {
        double s = 0.0;
        for (int b = 0; b < 32; ++b) s += (double)traces[b];
        out[131072] = (float)(s / 32.0 - 64.0);
    }
}

extern "C" void kernel_launch(void* const* d_in, const int* in_sizes, int n_in,
                              void* d_out, int out_size, void* d_ws, size_t ws_size,
                              hipStream_t stream)
{
    (void)in_sizes; (void)n_in; (void)out_size; (void)ws_size;

    const float* ds     = (const float*)d_in[0];
    const float* ve     = (const float*)d_in[1];
    const float* cc     = (const float*)d_in[2];
    const float* dge_w1 = (const float*)d_in[3];
    const float* dge_b1 = (const float*)d_in[4];
    const float* dge_w2 = (const float*)d_in[5];
    const float* dge_b2 = (const float*)d_in[6];
    const float* cge_w1 = (const float*)d_in[7];
    const float* cge_b1 = (const float*)d_in[8];
    const float* cge_w2 = (const float*)d_in[9];
    const float* cge_b2 = (const float*)d_in[10];
    const float* dep_w1 = (const float*)d_in[11];
    const float* dep_b1 = (const float*)d_in[12];
    const float* dep_w2 = (const float*)d_in[13];
    const float* dep_b2 = (const float*)d_in[14];
    const float* cep_w1 = (const float*)d_in[15];
    const float* cep_b1 = (const float*)d_in[16];
    const float* cep_w2 = (const float*)d_in[17];
    const float* cep_b2 = (const float*)d_in[18];
    const float* gw1    = (const float*)d_in[19];
    const float* gb1    = (const float*)d_in[20];
    const float* gw2    = (const float*)d_in[21];
    const float* gb2    = (const float*)d_in[22];
    const int*   nsamp  = (const int*)d_in[23];

    float* ws = (float*)d_ws;
    float* ctxproj = ws;                       // 6*32*256   = 49152
    float* fi_dep  = ctxproj + 49152;          // 32*64*256  = 524288
    float* fjt_dep = fi_dep + 524288;          // 524288
    float* fi_cep  = fjt_dep + 524288;         // 524288
    float* fjt_cep = fi_cep + 524288;          // 524288
    float* Wd      = fjt_cep + 524288;         // 131072
    float* Wc      = Wd + 131072;              // 131072
    float* entp    = Wc + 131072;              // 2048
    float* traces  = entp + 2048;              // 32

    float* outp = (float*)d_out;

    k0_ctx<<<dim3(32, 6), 256, 0, stream>>>(ds, cc, dge_w1, dge_b1, cge_w1, cge_b1,
                                            dep_w1, dep_b1, cep_w1, cep_b1, ctxproj);
    k1_encode<<<512, 512, 0, stream>>>(ve, dge_w1, dge_w2, dge_b2,
                                       cge_w1, cge_w2, cge_b2,
                                       dep_w1, cep_w1, ctxproj,
                                       fi_dep, fjt_dep, fi_cep, fjt_cep);
    k3_edges<<<1024, 512, 0, stream>>>(fi_dep, fjt_dep, fi_cep, fjt_cep,
                                       dep_w2, dep_b2, cep_w2, cep_b2,
                                       Wd, Wc, entp);
    k6_gate_expm<<<32, 512, 0, stream>>>(Wd, Wc, entp, gw1, gb1, gw2, gb2,
                                         nsamp, outp, traces);
    k7_acyc<<<1, 64, 0, stream>>>(traces, outp);
}